// Round 8
// baseline (808.632 us; speedup 1.0000x reference)
//
#include <hip/hip_runtime.h>

#define LVL 8
#define C 8192
#define D 128
#define P 8
#define F 4
#define K 4
#define S 4
#define NF 16384
#define NTOT (LVL*C)   // 65536

typedef __bf16 bf16;
typedef bf16 bf16x4 __attribute__((ext_vector_type(4)));
typedef bf16 bf16x8 __attribute__((ext_vector_type(8)));
typedef float f32x4 __attribute__((ext_vector_type(4)));

__device__ __forceinline__ f32x4 mfma16(bf16x8 a, bf16x8 b, f32x4 c) {
  return __builtin_amdgcn_mfma_f32_16x16x32_bf16(a, b, c, 0, 0, 0);
}
__device__ __forceinline__ bf16x4 b4(f32x4 v) {
  bf16x4 r; r[0]=(bf16)v[0]; r[1]=(bf16)v[1]; r[2]=(bf16)v[2]; r[3]=(bf16)v[3]; return r;
}
__device__ __forceinline__ float sigm(float x) { return __builtin_amdgcn_rcpf(1.f + __expf(-x)); }
__device__ __forceinline__ float tanh_(float x) { return 1.f - 2.f*__builtin_amdgcn_rcpf(1.f + __expf(2.f*x)); }

// Non-draining barrier: drain LDS ops (lgkmcnt) so hT/xT writes are visible,
// leave global gather loads in flight. Proven correct in R7.
__device__ __forceinline__ void bar() {
  asm volatile("s_waitcnt lgkmcnt(0)\n\ts_barrier" ::: "memory");
}

// ---- dtype-flexible accessors (f=1: float32 storage, f=0: bf16 storage) ----
__device__ __forceinline__ float ldf(const void* b, long i, int f) {
  return f ? ((const float*)b)[i] : (float)((const bf16*)b)[i];
}
__device__ __forceinline__ bf16x8 ldx8(const void* b, long i, int f) {
  if (f) {
    f32x4 a = *(const f32x4*)((const float*)b + i);
    f32x4 c = *(const f32x4*)((const float*)b + i + 4);
    bf16x8 r;
    r[0]=(bf16)a[0]; r[1]=(bf16)a[1]; r[2]=(bf16)a[2]; r[3]=(bf16)a[3];
    r[4]=(bf16)c[0]; r[5]=(bf16)c[1]; r[6]=(bf16)c[2]; r[7]=(bf16)c[3];
    return r;
  }
  return *(const bf16x8*)((const bf16*)b + i);
}
__device__ __forceinline__ f32x4 ld4f(const void* b, long i, int f) {
  if (f) return *(const f32x4*)((const float*)b + i);
  bf16x4 t = *(const bf16x4*)((const bf16*)b + i);
  f32x4 r; r[0]=(float)t[0]; r[1]=(float)t[1]; r[2]=(float)t[2]; r[3]=(float)t[3]; return r;
}
__device__ __forceinline__ void st4(void* b, long i, int f, f32x4 v) {
  if (f) *(f32x4*)((float*)b + i) = v;
  else   *(bf16x4*)((bf16*)b + i) = b4(v);
}

// ---------------------------------------------------------------------------
// GRU step split in two halves so two independent chains can interleave:
//   gru_mm:   MFMA accumulation only (acc arrays by ref)
//   gru_elem: elementwise + transposed h write
// SKIPU: t=0 peel (h0=0 -> U-MFMAs add exact 0 -> skip; bit-identical).
// ---------------------------------------------------------------------------
template<bool SKIPU>
__device__ __forceinline__ void gru_mm(
    const bf16x8 (&AU)[3][4], const bf16x8 (&AW)[3][4],
    const f32x4& zb, const f32x4& rb, const f32x4& nbx, const f32x4& nbh,
    const bf16 (* __restrict__ hbuf)[136], const bf16 (* __restrict__ xbuf)[136],
    int l15, int quad,
    f32x4 (&aZ)[2], f32x4 (&aR)[2], f32x4 (&aNx)[2], f32x4 (&aNh)[2])
{
#pragma unroll
  for (int nt = 0; nt < 2; nt++) { aZ[nt]=zb; aR[nt]=rb; aNx[nt]=nbx; aNh[nt]=nbh; }
#pragma unroll
  for (int kt = 0; kt < 4; kt++) {
    bf16x8 Bh[2], Bx[2];
#pragma unroll
    for (int nt = 0; nt < 2; nt++) {
      if (!SKIPU) Bh[nt] = *(const bf16x8*)&hbuf[nt*16 + l15][kt*32 + quad*8];
      Bx[nt] = *(const bf16x8*)&xbuf[nt*16 + l15][kt*32 + quad*8];
    }
#pragma unroll
    for (int nt = 0; nt < 2; nt++) {
      if (!SKIPU) aZ[nt]  = mfma16(AU[0][kt], Bh[nt], aZ[nt]);
      aZ[nt]  = mfma16(AW[0][kt], Bx[nt], aZ[nt]);
      if (!SKIPU) aR[nt]  = mfma16(AU[1][kt], Bh[nt], aR[nt]);
      aR[nt]  = mfma16(AW[1][kt], Bx[nt], aR[nt]);
      if (!SKIPU) aNh[nt] = mfma16(AU[2][kt], Bh[nt], aNh[nt]);
      aNx[nt] = mfma16(AW[2][kt], Bx[nt], aNx[nt]);
    }
  }
}

__device__ __forceinline__ void gru_elem(
    const f32x4 (&aZ)[2], const f32x4 (&aR)[2], const f32x4 (&aNx)[2], const f32x4 (&aNh)[2],
    int l15, int gc, f32x4 (&h)[2], bf16 (*hout)[136])
{
#pragma unroll
  for (int nt = 0; nt < 2; nt++) {
    f32x4 hn = h[nt];
#pragma unroll
    for (int i = 0; i < 4; i++) {
      float z = sigm(aZ[nt][i]);
      float r = sigm(aR[nt][i]);
      float n = tanh_(aNx[nt][i] + r*aNh[nt][i]);
      hn[i] = z*hn[i] + (1.f - z)*n;
    }
    h[nt] = hn;
    *(bf16x4*)&hout[nt*16 + l15][gc] = b4(hn);
  }
}

// ---------------------------------------------------------------------------
// Fused per-level kernel (mode 0): 256 blocks x 512 thr, 32 classes/block.
//   Phase A: fn GRU, 2 PAIRED passes (passes (0,1) then (2,3)); each paired
//     step interleaves two independent 32-seq GRU chains (A-MFMAs, B-MFMAs,
//     A-elem, B-elem, one barrier) -> half the serial segments of phase A.
//   Phase B: member GRU (32 seqs, T=13; steps 9-12 read feT)
//   Phase C: super GRU (32 seqs, T=5; step 4 = m from registers)
// mode 1 (glob): phase A only, ONE paired pass covering 64 seqs/block
//   (grid NF/64) -> glob time also ~halves.
// Per-sequence arithmetic identical to R7 (pairing only co-schedules
// independent sequences) -> bit-identical output.
// ---------------------------------------------------------------------------
__global__ __launch_bounds__(512, 1) void level_kernel(
    const bf16* __restrict__ pUt, const bf16* __restrict__ pWt, const float* __restrict__ b2p,
    const bf16* __restrict__ wtT,
    const bf16* __restrict__ mUt, const bf16* __restrict__ mWt, const float* __restrict__ b2m,
    const bf16* __restrict__ sUt, const bf16* __restrict__ sWt, const float* __restrict__ b2s,
    const void* __restrict__ empty_params, const void* __restrict__ empty_members,
    const void* __restrict__ tabR, int tabRf,
    const int* __restrict__ fpi, const int* __restrict__ fri,
    const int* __restrict__ ppi, const int* __restrict__ spi,
    void* __restrict__ out, long memfnEB, long tabEB,
    bf16* __restrict__ shadowW,
    const int* __restrict__ flagp, int mode)
{
  __shared__ __align__(16) bf16 hTa[2][32][136];
  __shared__ __align__(16) bf16 xTa[2][32][136];
  __shared__ __align__(16) bf16 hTb[2][32][136];
  __shared__ __align__(16) bf16 xTb[2][32][136];
  __shared__ __align__(16) bf16 feT[4][32][136];

  const int isf32 = *flagp;
  const int rf = (tabRf < 0) ? isf32 : tabRf;
  const int tid = threadIdx.x;
  const int w = tid >> 6;
  const int l15 = tid & 15;
  const int quad = (tid & 63) >> 4;
  const int gc = w*16 + quad*4;
  const int prow = tid >> 4;          // 0..31
  const int pc8 = (tid & 15) * 8;
  const int c0 = blockIdx.x * 32;

  bf16x8 AU[3][4], AW[3][4];
  f32x4 zb, rb, nbx, nbh;
  auto loadWB = [&](const bf16* Ut, const bf16* Wt, const float* b2) {
#pragma unroll
    for (int tr = 0; tr < 3; tr++)
#pragma unroll
      for (int kt = 0; kt < 4; kt++) {
        size_t o = (size_t)(tr*128 + w*16 + l15)*128 + kt*32 + quad*8;
        AU[tr][kt] = *(const bf16x8*)&Ut[o];
        AW[tr][kt] = *(const bf16x8*)&Wt[o];
      }
    zb  = *(const f32x4*)&b2[0*128 + gc];
    rb  = *(const f32x4*)&b2[1*128 + gc];
    nbx = *(const f32x4*)&b2[2*128 + gc];
    nbh = *(const f32x4*)&b2[3*128 + gc];
  };

  f32x4 hm[2];   // member result, carried into super phase

  // ================= Phase A: fn GRU + fe, PAIRED passes ====================
  loadWB(pUt, pWt, b2p);
  bf16x8 eP = ldx8(empty_params, pc8, isf32);

  // One paired pass: two independent 32-seq fn chains (a) and (b).
  // riv* gathers are issued at t=3 into the pend1 slots; after the loop the
  // pend0 registers hold the ret rows.
  auto fnpair = [&](int4 pivA, int4 pivB, int rivA, int rivB, int pa, int pb) {
    bf16x8 pA0 = ldx8(tabR, (long)pivA.x*128 + pc8, rf);
    bf16x8 pB0 = ldx8(tabR, (long)pivB.x*128 + pc8, rf);
    *(bf16x8*)&xTa[0][prow][pc8] = eP;
    *(bf16x8*)&xTb[0][prow][pc8] = eP;
    bar();

    f32x4 hA[2], hB[2];
#pragma unroll
    for (int nt = 0; nt < 2; nt++) {
      hA[nt][0]=0.f; hA[nt][1]=0.f; hA[nt][2]=0.f; hA[nt][3]=0.f;
      hB[nt][0]=0.f; hB[nt][1]=0.f; hB[nt][2]=0.f; hB[nt][3]=0.f;
    }
    bf16x8 pA1, pB1;
    int buf = 0;
#pragma unroll
    for (int t = 0; t < 5; t++) {
      if (t < 3) {
        int rnA = (t==0) ? pivA.y : (t==1) ? pivA.z : pivA.w;
        int rnB = (t==0) ? pivB.y : (t==1) ? pivB.z : pivB.w;
        pA1 = ldx8(tabR, (long)rnA*128 + pc8, rf);
        pB1 = ldx8(tabR, (long)rnB*128 + pc8, rf);
      } else if (t == 3) {   // prefetch ret rows into the pipe
        pA1 = ldx8(tabR, (long)rivA*128 + pc8, rf);
        pB1 = ldx8(tabR, (long)rivB*128 + pc8, rf);
      }
      f32x4 aZA[2], aRA[2], aNxA[2], aNhA[2];
      f32x4 aZB[2], aRB[2], aNxB[2], aNhB[2];
      if (t == 0) {
        gru_mm<true >(AU,AW,zb,rb,nbx,nbh,(const bf16(*)[136])hTa[buf],(const bf16(*)[136])xTa[0],l15,quad,aZA,aRA,aNxA,aNhA);
        gru_mm<true >(AU,AW,zb,rb,nbx,nbh,(const bf16(*)[136])hTb[buf],(const bf16(*)[136])xTb[0],l15,quad,aZB,aRB,aNxB,aNhB);
      } else {
        gru_mm<false>(AU,AW,zb,rb,nbx,nbh,(const bf16(*)[136])hTa[buf],(const bf16(*)[136])xTa[t&1],l15,quad,aZA,aRA,aNxA,aNhA);
        gru_mm<false>(AU,AW,zb,rb,nbx,nbh,(const bf16(*)[136])hTb[buf],(const bf16(*)[136])xTb[t&1],l15,quad,aZB,aRB,aNxB,aNhB);
      }
      gru_elem(aZA,aRA,aNxA,aNhA,l15,gc,hA,hTa[1-buf]);
      gru_elem(aZB,aRB,aNxB,aNhB,l15,gc,hB,hTb[1-buf]);
      if (t < 4) {
        *(bf16x8*)&xTa[(t+1)&1][prow][pc8] = pA0; pA0 = pA1;
        *(bf16x8*)&xTb[(t+1)&1][prow][pc8] = pB0; pB0 = pB1;
      }
      bar();
      buf ^= 1;
    }
    // ret rows (in pA0/pB0) -> xT*[0]
    *(bf16x8*)&xTa[0][prow][pc8] = pA0;
    *(bf16x8*)&xTb[0][prow][pc8] = pB0;
    bar();

    // fe GEMMs: out = [h | ret] @ W_fn (K=256), both passes interleaved
    f32x4 accA[2], accB[2];
#pragma unroll
    for (int nt = 0; nt < 2; nt++) {
      accA[nt][0]=0.f; accA[nt][1]=0.f; accA[nt][2]=0.f; accA[nt][3]=0.f;
      accB[nt][0]=0.f; accB[nt][1]=0.f; accB[nt][2]=0.f; accB[nt][3]=0.f;
    }
#pragma unroll
    for (int kt = 0; kt < 8; kt++) {
      bf16x8 A = *(const bf16x8*)&wtT[(size_t)(w*16 + l15)*256 + kt*32 + quad*8];
#pragma unroll
      for (int nt = 0; nt < 2; nt++) {
        bf16x8 Ba = (kt < 4) ? *(const bf16x8*)&hTa[buf][nt*16 + l15][kt*32 + quad*8]
                             : *(const bf16x8*)&xTa[0][nt*16 + l15][(kt-4)*32 + quad*8];
        accA[nt] = mfma16(A, Ba, accA[nt]);
        bf16x8 Bb = (kt < 4) ? *(const bf16x8*)&hTb[buf][nt*16 + l15][kt*32 + quad*8]
                             : *(const bf16x8*)&xTb[0][nt*16 + l15][(kt-4)*32 + quad*8];
        accB[nt] = mfma16(A, Bb, accB[nt]);
      }
    }
#pragma unroll
    for (int nt = 0; nt < 2; nt++) {
      long soA = mode ? ((long)blockIdx.x*64 + pa*32 + nt*16 + l15)
                      : ((long)(c0 + nt*16 + l15)*4 + pa);
      long soB = mode ? ((long)blockIdx.x*64 + pb*32 + nt*16 + l15)
                      : ((long)(c0 + nt*16 + l15)*4 + pb);
      st4(out, memfnEB + soA*128 + gc, isf32, accA[nt]);
      st4(out, memfnEB + soB*128 + gc, isf32, accB[nt]);
      if (!mode) {
        *(bf16x4*)&feT[pa][nt*16 + l15][gc] = b4(accA[nt]);
        *(bf16x4*)&feT[pb][nt*16 + l15][gc] = b4(accB[nt]);
      }
    }
    bar();   // protect xT/hT/feT before next pair / phase B
  };

  if (mode) {
    long sA = (long)blockIdx.x*64 + prow;
    long sB = sA + 32;
    int4 pA = *(const int4*)&fpi[sA*4];
    int4 pB = *(const int4*)&fpi[sB*4];
    fnpair(pA, pB, fri[sA], fri[sB], 0, 1);
    return;
  }
  {
    long s4 = (long)(c0 + prow)*4;
    {
      int4 p0 = *(const int4*)&fpi[(s4+0)*4];
      int4 p1 = *(const int4*)&fpi[(s4+1)*4];
      int4 rr = *(const int4*)&fri[s4];
      fnpair(p0, p1, rr.x, rr.y, 0, 1);
    }
    {
      int4 p2 = *(const int4*)&fpi[(s4+2)*4];
      int4 p3 = *(const int4*)&fpi[(s4+3)*4];
      int4 rr = *(const int4*)&fri[s4];
      fnpair(p2, p3, rr.z, rr.w, 2, 3);
    }
  }

  // ================= Phase B: member GRU (T=13) =============================
  loadWB(mUt, mWt, b2m);
  int4 ma  = *(const int4*)&ppi[(size_t)(c0 + prow)*8];
  int4 mb2 = *(const int4*)&ppi[(size_t)(c0 + prow)*8 + 4];
  bf16x8 pendB0 = ldx8(tabR, (long)ma.x*128 + pc8, rf);   // x for step 1
  bf16x8 eM = ldx8(empty_members, pc8, isf32);
  *(bf16x8*)&xTa[0][prow][pc8] = eM;
  bar();

#pragma unroll
  for (int nt = 0; nt < 2; nt++) { hm[nt][0]=0.f; hm[nt][1]=0.f; hm[nt][2]=0.f; hm[nt][3]=0.f; }
  {
    bf16x8 pendB1;
    int buf = 0;
#pragma unroll
    for (int t = 0; t < 13; t++) {
      if (t < 7) {
        int rn = (t==0)?ma.y:(t==1)?ma.z:(t==2)?ma.w:(t==3)?mb2.x:(t==4)?mb2.y:(t==5)?mb2.z:mb2.w;
        pendB1 = ldx8(tabR, (long)rn*128 + pc8, rf);
      }
      const bf16 (*xb)[136] = (t < 9) ? (const bf16(*)[136])xTa[t&1]
                                      : (const bf16(*)[136])feT[t-9];
      f32x4 aZ[2], aR[2], aNx[2], aNh[2];
      if (t == 0)
        gru_mm<true >(AU,AW,zb,rb,nbx,nbh,(const bf16(*)[136])hTa[buf],xb,l15,quad,aZ,aR,aNx,aNh);
      else
        gru_mm<false>(AU,AW,zb,rb,nbx,nbh,(const bf16(*)[136])hTa[buf],xb,l15,quad,aZ,aR,aNx,aNh);
      gru_elem(aZ,aR,aNx,aNh,l15,gc,hm,hTa[1-buf]);
      if (t < 8) { *(bf16x8*)&xTa[(t+1)&1][prow][pc8] = pendB0; pendB0 = pendB1; }
      bar();
      buf ^= 1;
    }
  }

  // ================= Phase C: super GRU (T=5) ===============================
  loadWB(sUt, sWt, b2s);
  int4 sa = *(const int4*)&spi[(size_t)(c0 + prow)*4];
  bf16x8 x0v    = ldx8(tabR, (long)sa.x*128 + pc8, rf);
  bf16x8 pendC0 = ldx8(tabR, (long)sa.y*128 + pc8, rf);
  *(bf16x8*)&xTa[0][prow][pc8] = x0v;
  bar();

  f32x4 hs[2];
#pragma unroll
  for (int nt = 0; nt < 2; nt++) { hs[nt][0]=0.f; hs[nt][1]=0.f; hs[nt][2]=0.f; hs[nt][3]=0.f; }
  {
    bf16x8 pendC1;
    int buf = 0;
#pragma unroll
    for (int t = 0; t < 5; t++) {
      if (t < 2) {
        int rn = (t==0) ? sa.z : sa.w;
        pendC1 = ldx8(tabR, (long)rn*128 + pc8, rf);
      }
      f32x4 aZ[2], aR[2], aNx[2], aNh[2];
      if (t == 0)
        gru_mm<true >(AU,AW,zb,rb,nbx,nbh,(const bf16(*)[136])hTa[buf],(const bf16(*)[136])xTa[0],l15,quad,aZ,aR,aNx,aNh);
      else
        gru_mm<false>(AU,AW,zb,rb,nbx,nbh,(const bf16(*)[136])hTa[buf],(const bf16(*)[136])xTa[t&1],l15,quad,aZ,aR,aNx,aNh);
      gru_elem(aZ,aR,aNx,aNh,l15,gc,hs,hTa[1-buf]);
      if (t < 3) { *(bf16x8*)&xTa[(t+1)&1][prow][pc8] = pendC0; pendC0 = pendC1; }
      else if (t == 3) {   // stage m (registers) as x for step 4
#pragma unroll
        for (int nt = 0; nt < 2; nt++) *(bf16x4*)&xTa[0][nt*16 + l15][gc] = b4(hm[nt]);
      }
      bar();
      buf ^= 1;
    }
  }
#pragma unroll
  for (int nt = 0; nt < 2; nt++) {
    long row = (long)(c0 + nt*16 + l15);
    st4(out, tabEB + row*128 + gc, isf32, hs[nt]);
    if (shadowW) *(bf16x4*)&shadowW[row*128 + gc] = b4(hs[nt]);
  }
}

// ---------------------------------------------------------------------------
__global__ void detect_kernel(const void* be, int* flag) {
  if (threadIdx.x == 0 && blockIdx.x == 0) {
    const unsigned short* u = (const unsigned short*)be;
    int f = 0;
    for (int i = 0; i < 128; i++) {
      unsigned e = (u[i] >> 7) & 0xFF;
      if (e >= 128) f = 1;
    }
    *flag = f;
  }
}

__global__ void convert_kernel(const void* pW, const void* pU, const void* mW, const void* mU,
                               const void* sW, const void* sU, const void* W_fn,
                               const void* pb, const void* mb, const void* sb,
                               bf16* pWt, bf16* pUt, bf16* mWt, bf16* mUt,
                               bf16* sWt, bf16* sUt, bf16* wtT,
                               float* b2p, float* b2m, float* b2s,
                               const int* flagp) {
  const int f = *flagp;
  int i = blockIdx.x*256 + threadIdx.x;
  const int TT = 384*128;
  if (i < 6*TT) {
    int which = i / TT, j = i - which*TT;
    int c = j >> 7, k = j & 127;
    const void* src = (which==0)?pW:(which==1)?pU:(which==2)?mW:(which==3)?mU:(which==4)?sW:sU;
    bf16* dst = (which==0)?pWt:(which==1)?pUt:(which==2)?mWt:(which==3)?mUt:(which==4)?sWt:sUt;
    dst[c*128 + k] = (bf16)ldf(src, (long)k*384 + c, f);
    return;
  }
  i -= 6*TT;
  if (i < 128*256) { int c = i >> 8, k = i & 255; wtT[c*256 + k] = (bf16)ldf(W_fn, (long)k*128 + c, f); return; }
  i -= 128*256;
  if (i < 3*512) {
    int which = i >> 9, j = i & 511;
    const void* b = (which==0)?pb:(which==1)?mb:sb;
    float* dst = (which==0)?b2p:(which==1)?b2m:b2s;
    int g = j >> 7, cc = j & 127;
    float v;
    if (g == 0)      v = ldf(b, cc, f)       + ldf(b, 384 + cc, f);
    else if (g == 1) v = ldf(b, 128 + cc, f) + ldf(b, 512 + cc, f);
    else if (g == 2) v = ldf(b, 256 + cc, f);
    else             v = ldf(b, 640 + cc, f);
    dst[j] = v;
  }
}

__global__ void level0_kernel(const int* __restrict__ basic_ids, const void* basic_emb,
                              void* out, bf16* __restrict__ shadow,
                              const int* __restrict__ flagp) {
  const int f = *flagp;
  int i = blockIdx.x*256 + threadIdx.x;   // < C*32
  int row = i >> 5, c4 = (i & 31) * 4;
  f32x4 v = ld4f(basic_emb, (long)basic_ids[row]*128 + c4, f);
  st4(out, (long)row*128 + c4, f, v);
  if (shadow) *(bf16x4*)&shadow[(long)row*128 + c4] = b4(v);
}

// ---------------------------------------------------------------------------
extern "C" void kernel_launch(void* const* d_in, const int* in_sizes, int n_in,
                              void* d_out, int out_size, void* d_ws, size_t ws_size,
                              hipStream_t stream) {
  const int* basic_ids      = (const int*)d_in[0];
  const int* prop_idx       = (const int*)d_in[1];
  const int* func_param_idx = (const int*)d_in[2];
  const int* func_ret_idx   = (const int*)d_in[3];
  const int* super_idx      = (const int*)d_in[4];
  const int* glob_param_idx = (const int*)d_in[5];
  const int* glob_ret_idx   = (const int*)d_in[6];
  const void* basic_emb     = d_in[7];
  const void* empty_params  = d_in[8];
  const void* empty_members = d_in[9];
  const void* W_fn = d_in[10];
  const void* pW = d_in[11]; const void* pU = d_in[12]; const void* pb = d_in[13];
  const void* mW = d_in[14]; const void* mU = d_in[15]; const void* mb = d_in[16];
  const void* sW = d_in[17]; const void* sU = d_in[18]; const void* sb = d_in[19];

  // d_out element layout: table [NTOT*128] | glob [NF*128] | memfn [7*C*F*128]
  const long GB = (long)NTOT*128;
  const long MB0 = GB + (long)NF*128;
  auto FEB = [&](int l) { return MB0 + (long)(l-1)*C*F*128; };

  char* wp = (char*)d_ws;
  auto carve = [&](size_t bytes) { char* p = wp; wp += (bytes + 255) & ~(size_t)255; return p; };
  int*  flag = (int*)carve(256);
  bf16* pWt = (bf16*)carve(384*128*2);
  bf16* pUt = (bf16*)carve(384*128*2);
  bf16* mWt = (bf16*)carve(384*128*2);
  bf16* mUt = (bf16*)carve(384*128*2);
  bf16* sWt = (bf16*)carve(384*128*2);
  bf16* sUt = (bf16*)carve(384*128*2);
  bf16* wtT = (bf16*)carve(128*256*2);
  float* b2p = (float*)carve(512*4);
  float* b2m = (float*)carve(512*4);
  float* b2s = (float*)carve(512*4);
  bf16* shadow = (bf16*)carve((size_t)NTOT*128*2);   // bf16 mirror of table, ~16.8 MB

  const bool useShadow = ((size_t)(wp - (char*)d_ws) <= ws_size);
  const void* tabR = useShadow ? (const void*)shadow : (const void*)d_out;
  const int tabRf  = useShadow ? 0 : -1;             // -1: use detected dtype flag
  bf16* shadowL0   = useShadow ? shadow : (bf16*)nullptr;

  detect_kernel<<<1, 64, 0, stream>>>(basic_emb, flag);
  {
    int total = 6*384*128 + 128*256 + 3*512;
    convert_kernel<<<(total + 255)/256, 256, 0, stream>>>(pW, pU, mW, mU, sW, sU, W_fn,
                                                          pb, mb, sb,
                                                          pWt, pUt, mWt, mUt, sWt, sUt, wtT,
                                                          b2p, b2m, b2s, flag);
  }
  level0_kernel<<<(C*32)/256, 256, 0, stream>>>(basic_ids, basic_emb, d_out, shadowL0, flag);

  for (int l = 1; l < LVL; l++) {
    level_kernel<<<C/32, 512, 0, stream>>>(
        pUt, pWt, b2p, wtT, mUt, mWt, b2m, sUt, sWt, b2s,
        empty_params, empty_members,
        tabR, tabRf,
        func_param_idx + (size_t)(l-1)*C*F*K,
        func_ret_idx   + (size_t)(l-1)*C*F,
        prop_idx       + (size_t)(l-1)*C*P,
        super_idx      + (size_t)(l-1)*C*S,
        d_out, FEB(l), (long)l*C*128,
        useShadow ? shadow + (size_t)l*C*128 : (bf16*)nullptr,
        flag, 0);
  }

  // global functions (NF seqs, T=5, 64 seqs/block paired) -> glob
  level_kernel<<<NF/64, 512, 0, stream>>>(
      pUt, pWt, b2p, wtT, mUt, mWt, b2m, sUt, sWt, b2s,
      empty_params, empty_members,
      tabR, tabRf,
      glob_param_idx, glob_ret_idx, nullptr, nullptr,
      d_out, GB, 0, (bf16*)nullptr,
      flag, 1);
}